// Round 3
// baseline (1483.257 us; speedup 1.0000x reference)
//
#include <hip/hip_runtime.h>
#include <math.h>

#define N_ROWS 16384
#define K_CODES 4096
#define D_DIM 512
#define NCHUNK 8
#define KCHUNK (K_CODES / NCHUNK)
#define MARGIN 5e-4f

typedef unsigned int uint32;
typedef unsigned short ushort16;
typedef __attribute__((ext_vector_type(8))) short short8;
typedef __attribute__((ext_vector_type(4))) float f32x4;

__device__ __forceinline__ float fmul_(float a, float b) { return __fmul_rn(a, b); }
__device__ __forceinline__ float fadd_(float a, float b) { return __fadd_rn(a, b); }

// ---------------------------------------------------------------- rownorm
// Bit-exact emulation of np.sum(x*x, axis=1), rows of 512 (verified R2).
__global__ void rownorm_np_kernel(const float* __restrict__ src, int nrows,
                                  float* __restrict__ out) {
    int gid = blockIdx.x * blockDim.x + threadIdx.x;
    int row = gid >> 2;
    int blk = gid & 3;
    if (row >= nrows) return;
    const float4* p = (const float4*)(src + (size_t)row * D_DIM + blk * 128);
    float4 v0 = p[0], v1 = p[1];
    float r0 = fmul_(v0.x, v0.x), r1 = fmul_(v0.y, v0.y);
    float r2 = fmul_(v0.z, v0.z), r3 = fmul_(v0.w, v0.w);
    float r4 = fmul_(v1.x, v1.x), r5 = fmul_(v1.y, v1.y);
    float r6 = fmul_(v1.z, v1.z), r7 = fmul_(v1.w, v1.w);
#pragma unroll
    for (int i = 1; i < 16; i++) {
        float4 w0 = p[2 * i], w1 = p[2 * i + 1];
        r0 = fadd_(r0, fmul_(w0.x, w0.x));
        r1 = fadd_(r1, fmul_(w0.y, w0.y));
        r2 = fadd_(r2, fmul_(w0.z, w0.z));
        r3 = fadd_(r3, fmul_(w0.w, w0.w));
        r4 = fadd_(r4, fmul_(w1.x, w1.x));
        r5 = fadd_(r5, fmul_(w1.y, w1.y));
        r6 = fadd_(r6, fmul_(w1.z, w1.z));
        r7 = fadd_(r7, fmul_(w1.w, w1.w));
    }
    float s = fadd_(fadd_(fadd_(r0, r1), fadd_(r2, r3)),
                    fadd_(fadd_(r4, r5), fadd_(r6, r7)));
    float u = __shfl_down(s, 1, 64);
    float t = fadd_(s, u);
    float w = __shfl_down(t, 2, 64);
    float tot = fadd_(t, w);
    if (blk == 0) out[row] = tot;
}

// ---------------------------------------------------------------- cvt bf16
__device__ __forceinline__ ushort16 f2bf(float x) {
    uint32 u = __float_as_uint(x);
    return (ushort16)((u + 0x7fffu + ((u >> 16) & 1u)) >> 16);   // RNE
}
__global__ void cvt_bf16_kernel(const float* __restrict__ src,
                                ushort16* __restrict__ dst, int n4) {
    int i = blockIdx.x * blockDim.x + threadIdx.x;
    if (i >= n4) return;
    float4 v = ((const float4*)src)[i];
    ushort4 o;
    o.x = f2bf(v.x); o.y = f2bf(v.y); o.z = f2bf(v.z); o.w = f2bf(v.w);
    ((ushort4*)dst)[i] = o;
}

// ---------------------------------------------------------------- phase 1
// bf16 MFMA coarse GEMM + running-min candidate bitmask.
// grid (8 chunks, 128 row tiles), 256 thr, tile 128x128, BK=32, D=512.
__global__ __launch_bounds__(256) void coarse_kernel(
    const ushort16* __restrict__ zb, const ushort16* __restrict__ cbb,
    const float* __restrict__ cnorm, uint32* __restrict__ mask_g) {
    __shared__ alignas(16) ushort16 Ab[128 * 32];
    __shared__ alignas(16) ushort16 Bb[128 * 32];
    __shared__ alignas(16) uint32 msk[128 * 16];

    const int t = threadIdx.x;
    const int bx = blockIdx.x;
    const int by = blockIdx.y;
    const int row0 = by * 128, k0 = bx * KCHUNK;
    const int w = t >> 6, lane = t & 63;
    const int wx = w & 1, wy = w >> 1;
    const int l15 = lane & 15, quad = lane >> 4;

    for (int i = t; i < 128 * 16; i += 256) msk[i] = 0u;

    float minv[16];
#pragma unroll
    for (int i = 0; i < 16; i++) minv[i] = 3.4e38f;

    for (int kt = 0; kt < 4; kt++) {
        f32x4 acc[4][4];
#pragma unroll
        for (int i = 0; i < 4; i++)
#pragma unroll
            for (int j = 0; j < 4; j++) acc[i][j] = (f32x4){0.f, 0.f, 0.f, 0.f};

        for (int dt = 0; dt < 16; dt++) {
            __syncthreads();
#pragma unroll
            for (int q = 0; q < 2; q++) {
                int s = q * 256 + t;
                const ushort16* ga = zb + (size_t)(row0 + (s >> 2)) * D_DIM + dt * 32 + (s & 3) * 8;
                __builtin_amdgcn_global_load_lds(
                    (const __attribute__((address_space(1))) void*)ga,
                    (__attribute__((address_space(3))) void*)((char*)Ab + q * 4096 + w * 1024),
                    16, 0, 0);
                const ushort16* gb = cbb + (size_t)(k0 + kt * 128 + (s >> 2)) * D_DIM + dt * 32 + (s & 3) * 8;
                __builtin_amdgcn_global_load_lds(
                    (const __attribute__((address_space(1))) void*)gb,
                    (__attribute__((address_space(3))) void*)((char*)Bb + q * 4096 + w * 1024),
                    16, 0, 0);
            }
            __syncthreads();
            short8 a[4], b[4];
#pragma unroll
            for (int i = 0; i < 4; i++)
                a[i] = *(const short8*)((char*)Ab + (wy * 64 + i * 16 + l15) * 64 + quad * 16);
#pragma unroll
            for (int j = 0; j < 4; j++)
                b[j] = *(const short8*)((char*)Bb + (wx * 64 + j * 16 + l15) * 64 + quad * 16);
#pragma unroll
            for (int i = 0; i < 4; i++)
#pragma unroll
                for (int j = 0; j < 4; j++)
                    acc[i][j] = __builtin_amdgcn_mfma_f32_16x16x32_bf16(a[i], b[j], acc[i][j], 0, 0, 0);
        }
        // epilogue: coarse s = cc - 2*dot; candidate bits vs running min
#pragma unroll
        for (int j = 0; j < 4; j++) {
            int cl = kt * 128 + wx * 64 + j * 16 + l15;
            float cn = cnorm[k0 + cl];
#pragma unroll
            for (int i = 0; i < 4; i++) {
#pragma unroll
                for (int r = 0; r < 4; r++) {
                    int rl = wy * 64 + i * 16 + quad * 4 + r;
                    float s = fmaf(-2.f, acc[i][j][r], cn);
                    int slot = i * 4 + r;
                    if (s <= minv[slot] + MARGIN)
                        atomicOr(&msk[rl * 16 + (cl >> 5)], 1u << (cl & 31));
                    if (s < minv[slot]) minv[slot] = s;
                }
            }
        }
    }
    __syncthreads();
    {
        int r = t >> 1, part = t & 1;
        uint4 a = *(const uint4*)&msk[r * 16 + part * 8];
        uint4 b2 = *(const uint4*)&msk[r * 16 + part * 8 + 4];
        uint4* dst = (uint4*)(mask_g + ((size_t)(row0 + r) * NCHUNK + bx) * 16 + part * 8);
        dst[0] = a; dst[1] = b2;
    }
}

// ---------------------------------------------------------------- phase 2
// Per row: expand candidate bits, exact numpy-fp32 dist for each, first-
// occurrence argmin, then fused gather/STE write + rowsum.
__global__ __launch_bounds__(256) void refine_kernel(
    const float* __restrict__ z, const float* __restrict__ cb,
    const float* __restrict__ zz, const float* __restrict__ cnorm,
    const uint32* __restrict__ mask_g,
    float* __restrict__ out_zq, float* __restrict__ out_idx,
    float* __restrict__ rowsum) {
    __shared__ uint32 mwords[128];
    __shared__ int cnt[128];
    __shared__ int prefix[129];
    __shared__ int clist[4096];
    __shared__ float wbv[4];
    __shared__ int wbi[4];
    __shared__ float red[256];
    __shared__ int bcast;

    const int row = blockIdx.x;
    const int t = threadIdx.x;
    const int w = t >> 6, lane = t & 63;

    if (t < 128) {
        mwords[t] = mask_g[(size_t)row * 128 + t];
        cnt[t] = __popc(mwords[t]);
    }
    __syncthreads();
    if (t == 0) {
        int s = 0;
        for (int i = 0; i < 128; i++) { prefix[i] = s; s += cnt[i]; }
        prefix[128] = s;
    }
    __syncthreads();
    const int C = prefix[128];
    if (t < 128) {
        uint32 wd = mwords[t];
        int base = prefix[t];
        int col0 = t * 32;
        while (wd) {
            int b = __ffs(wd) - 1;
            wd &= wd - 1;
            clist[base++] = col0 + b;
        }
    }
    __syncthreads();

    const float* zr = z + (size_t)row * D_DIM;
    float4 z0 = *(const float4*)(zr + lane * 8);
    float4 z1 = *(const float4*)(zr + lane * 8 + 4);
    float zzr = zz[row];

    float bv = 3.4e38f;
    int bi = 0x7fffffff;
    for (int ci = w; ci < C; ci += 4) {       // each wave: ascending indices
        int k = clist[ci];
        const float* cr = cb + (size_t)k * D_DIM;
        float4 c0 = *(const float4*)(cr + lane * 8);
        float4 c1 = *(const float4*)(cr + lane * 8 + 4);
        float d = fmul_(z0.x, c0.x);
        d = fmaf(z0.y, c0.y, d); d = fmaf(z0.z, c0.z, d); d = fmaf(z0.w, c0.w, d);
        d = fmaf(z1.x, c1.x, d); d = fmaf(z1.y, c1.y, d);
        d = fmaf(z1.z, c1.z, d); d = fmaf(z1.w, c1.w, d);
#pragma unroll
        for (int off = 1; off < 64; off <<= 1)
            d = fadd_(d, __shfl_xor(d, off, 64));
        float dist = fmaf(-2.f, d, fadd_(zzr, cnorm[k]));
        if (dist < bv) { bv = dist; bi = k; }   // strict <: first occurrence
    }
    if (lane == 0) { wbv[w] = bv; wbi[w] = bi; }
    __syncthreads();
    if (t == 0) {
        float B = wbv[0]; int I = wbi[0];
#pragma unroll
        for (int i = 1; i < 4; i++) {
            float v = wbv[i]; int ii = wbi[i];
            if (v < B || (v == B && ii < I)) { B = v; I = ii; }
        }
        bcast = I;
        out_idx[row] = (float)I;
    }
    __syncthreads();
    const int K = bcast;
    const float* cq = cb + (size_t)K * D_DIM;
    float2 zv2 = *(const float2*)(zr + t * 2);
    float2 cv2 = *(const float2*)(cq + t * 2);
    float2 o;
    o.x = fadd_(zv2.x, __fsub_rn(cv2.x, zv2.x));
    o.y = fadd_(zv2.y, __fsub_rn(cv2.y, zv2.y));
    *(float2*)(out_zq + (size_t)row * D_DIM + t * 2) = o;
    float dx = zv2.x - cv2.x, dy = zv2.y - cv2.y;
    red[t] = dx * dx + dy * dy;
    __syncthreads();
    for (int st = 128; st; st >>= 1) {
        if (t < st) red[t] += red[t + st];
        __syncthreads();
    }
    if (t == 0) rowsum[row] = red[0];
}

// ---------------------------------------------------------------- loss
__global__ void loss_kernel(const float* __restrict__ rowsum,
                            float* __restrict__ out_loss) {
    __shared__ float sm[256];
    float s = 0.f;
    for (int i = threadIdx.x; i < N_ROWS; i += 256) s += rowsum[i];
    sm[threadIdx.x] = s;
    __syncthreads();
    for (int st = 128; st; st >>= 1) {
        if (threadIdx.x < st) sm[threadIdx.x] += sm[threadIdx.x + st];
        __syncthreads();
    }
    if (threadIdx.x == 0)
        *out_loss = 1.25f * sm[0] / (float)(N_ROWS * D_DIM);
}

// ================================================================ fallback
// (verified round-2 fp32 path, used only if ws_size too small)
#define BM 128
#define BN 128
#define BK 16
#define TM 8
#define TN 8

__global__ __launch_bounds__(256, 4) void vq_argmin_kernel(
    const float* __restrict__ z, const float* __restrict__ cb,
    const float* __restrict__ zz, const float* __restrict__ cnorm,
    float* __restrict__ pval, int* __restrict__ pidx) {
    __shared__ float As[BK][BM + 4];
    __shared__ float Bs[BK][BN + 4];
    __shared__ float rv[BM][17];
    __shared__ int   ri[BM][17];

    const int bx = blockIdx.x;
    const int by = blockIdx.y;
    const int row0 = by * BM;
    const int k0 = bx * KCHUNK;
    const int t = threadIdx.x;
    const int tx = t & 15;
    const int ty = t >> 4;

    float minv[TM];
    int   mini[TM];
#pragma unroll
    for (int i = 0; i < TM; i++) { minv[i] = 3.4e38f; mini[i] = 0; }
    float zrow[TM];
#pragma unroll
    for (int i = 0; i < TM; i++) zrow[i] = zz[row0 + ty * TM + i];
    const int sr = t >> 1;
    const int sdq = (t & 1) * 8;

    for (int kt = 0; kt < KCHUNK / BN; kt++) {
        const int col0 = k0 + kt * BN;
        float acc[TM][TN];
#pragma unroll
        for (int i = 0; i < TM; i++)
#pragma unroll
            for (int j = 0; j < TN; j++) acc[i][j] = 0.f;
        for (int dt = 0; dt < D_DIM; dt += BK) {
            {
                const float* src = z + (size_t)(row0 + sr) * D_DIM + dt + sdq;
                float4 v0 = *(const float4*)(src);
                float4 v1 = *(const float4*)(src + 4);
                As[sdq + 0][sr] = v0.x; As[sdq + 1][sr] = v0.y;
                As[sdq + 2][sr] = v0.z; As[sdq + 3][sr] = v0.w;
                As[sdq + 4][sr] = v1.x; As[sdq + 5][sr] = v1.y;
                As[sdq + 6][sr] = v1.z; As[sdq + 7][sr] = v1.w;
                const float* srcb = cb + (size_t)(col0 + sr) * D_DIM + dt + sdq;
                float4 w0 = *(const float4*)(srcb);
                float4 w1 = *(const float4*)(srcb + 4);
                Bs[sdq + 0][sr] = w0.x; Bs[sdq + 1][sr] = w0.y;
                Bs[sdq + 2][sr] = w0.z; Bs[sdq + 3][sr] = w0.w;
                Bs[sdq + 4][sr] = w1.x; Bs[sdq + 5][sr] = w1.y;
                Bs[sdq + 6][sr] = w1.z; Bs[sdq + 7][sr] = w1.w;
            }
            __syncthreads();
#pragma unroll
            for (int d = 0; d < BK; d++) {
                float a[TM], b[TN];
#pragma unroll
                for (int i = 0; i < TM; i++) a[i] = As[d][ty * TM + i];
#pragma unroll
                for (int j = 0; j < TN; j++) b[j] = Bs[d][tx * TN + j];
#pragma unroll
                for (int i = 0; i < TM; i++)
#pragma unroll
                    for (int j = 0; j < TN; j++)
                        acc[i][j] = fmaf(a[i], b[j], acc[i][j]);
            }
            __syncthreads();
        }
#pragma unroll
        for (int j = 0; j < TN; j++) {
            const int col = col0 + tx * TN + j;
            const float cn = cnorm[col];
#pragma unroll
            for (int i = 0; i < TM; i++) {
                float s1 = fadd_(zrow[i], cn);
                float s = fmaf(-2.f, acc[i][j], s1);
                if (s < minv[i]) { minv[i] = s; mini[i] = col; }
            }
        }
    }
#pragma unroll
    for (int i = 0; i < TM; i++) {
        rv[ty * TM + i][tx] = minv[i];
        ri[ty * TM + i][tx] = mini[i];
    }
    __syncthreads();
    if (t < BM) {
        float bv = rv[t][0];
        int   bi = ri[t][0];
#pragma unroll
        for (int x = 1; x < 16; x++) {
            float v = rv[t][x]; int ii = ri[t][x];
            if (v < bv || (v == bv && ii < bi)) { bv = v; bi = ii; }
        }
        pval[(size_t)(row0 + t) * NCHUNK + bx] = bv;
        pidx[(size_t)(row0 + t) * NCHUNK + bx] = bi;
    }
}

__global__ void finalize_kernel(const float* __restrict__ z,
                                const float* __restrict__ cb,
                                const float* __restrict__ pval,
                                const int* __restrict__ pidx,
                                float* __restrict__ out_zq,
                                float* __restrict__ out_idx,
                                float* __restrict__ rowsum) {
    int row = (blockIdx.x * blockDim.x + threadIdx.x) >> 6;
    int lane = threadIdx.x & 63;
    if (row >= N_ROWS) return;
    float bv = pval[(size_t)row * NCHUNK];
    int   bi = pidx[(size_t)row * NCHUNK];
#pragma unroll
    for (int c = 1; c < NCHUNK; c++) {
        float v = pval[(size_t)row * NCHUNK + c];
        int  ii = pidx[(size_t)row * NCHUNK + c];
        if (v < bv || (v == bv && ii < bi)) { bv = v; bi = ii; }
    }
    const float4* zr = (const float4*)(z + (size_t)row * D_DIM);
    const float4* cr = (const float4*)(cb + (size_t)bi * D_DIM);
    float4* orow = (float4*)(out_zq + (size_t)row * D_DIM);
    float s = 0.f;
#pragma unroll
    for (int i = 0; i < 2; i++) {
        float4 zv = zr[i * 64 + lane];
        float4 cv = cr[i * 64 + lane];
        float4 o;
        o.x = fadd_(zv.x, __fsub_rn(cv.x, zv.x));
        o.y = fadd_(zv.y, __fsub_rn(cv.y, zv.y));
        o.z = fadd_(zv.z, __fsub_rn(cv.z, zv.z));
        o.w = fadd_(zv.w, __fsub_rn(cv.w, zv.w));
        orow[i * 64 + lane] = o;
        float dx = zv.x - cv.x, dy = zv.y - cv.y;
        float dz = zv.z - cv.z, dw = zv.w - cv.w;
        s += dx * dx + dy * dy + dz * dz + dw * dw;
    }
#pragma unroll
    for (int off = 32; off; off >>= 1) s += __shfl_down(s, off, 64);
    if (lane == 0) {
        rowsum[row] = s;
        out_idx[row] = (float)bi;
    }
}

// ---------------------------------------------------------------- launch
extern "C" void kernel_launch(void* const* d_in, const int* in_sizes, int n_in,
                              void* d_out, int out_size, void* d_ws, size_t ws_size,
                              hipStream_t stream) {
    const float* z  = (const float*)d_in[0];
    const float* cb = (const float*)d_in[1];
    float* out      = (float*)d_out;
    float* out_zq   = out;
    float* out_idx  = out + (size_t)N_ROWS * D_DIM;
    float* out_loss = out_idx + N_ROWS;

    // workspace layout (new path)
    float*    zz     = (float*)d_ws;                       // 16384
    float*    cnorm  = zz + N_ROWS;                        // 4096
    float*    rowsum = cnorm + K_CODES;                    // 16384
    ushort16* z_bf   = (ushort16*)(rowsum + N_ROWS);       // 16384*512 u16
    ushort16* cb_bf  = z_bf + (size_t)N_ROWS * D_DIM;      // 4096*512 u16
    uint32*   mask_g = (uint32*)(cb_bf + (size_t)K_CODES * D_DIM);  // 16384*128 u32
    const size_t WS_NEEDED = (size_t)(N_ROWS + K_CODES + N_ROWS) * 4
                           + (size_t)N_ROWS * D_DIM * 2
                           + (size_t)K_CODES * D_DIM * 2
                           + (size_t)N_ROWS * 128 * 4;

    if (ws_size >= WS_NEEDED) {
        cvt_bf16_kernel<<<(N_ROWS * D_DIM / 4 + 255) / 256, 256, 0, stream>>>(z, z_bf, N_ROWS * D_DIM / 4);
        cvt_bf16_kernel<<<(K_CODES * D_DIM / 4 + 255) / 256, 256, 0, stream>>>(cb, cb_bf, K_CODES * D_DIM / 4);
        rownorm_np_kernel<<<(N_ROWS * 4) / 256, 256, 0, stream>>>(z, N_ROWS, zz);
        rownorm_np_kernel<<<(K_CODES * 4) / 256, 256, 0, stream>>>(cb, K_CODES, cnorm);

        dim3 g1(NCHUNK, N_ROWS / 128);
        coarse_kernel<<<g1, 256, 0, stream>>>(z_bf, cb_bf, cnorm, mask_g);
        refine_kernel<<<N_ROWS, 256, 0, stream>>>(z, cb, zz, cnorm, mask_g,
                                                  out_zq, out_idx, rowsum);
        loss_kernel<<<1, 256, 0, stream>>>(rowsum, out_loss);
    } else {
        // fallback: verified round-2 fp32 path (~1 MB ws)
        float* pval   = rowsum + N_ROWS;
        int*   pidx   = (int*)(pval + (size_t)N_ROWS * NCHUNK);
        rownorm_np_kernel<<<(N_ROWS * 4) / 256, 256, 0, stream>>>(z, N_ROWS, zz);
        rownorm_np_kernel<<<(K_CODES * 4) / 256, 256, 0, stream>>>(cb, K_CODES, cnorm);
        dim3 g2(NCHUNK, N_ROWS / BM);
        vq_argmin_kernel<<<g2, 256, 0, stream>>>(z, cb, zz, cnorm, pval, pidx);
        finalize_kernel<<<N_ROWS / 4, 256, 0, stream>>>(z, cb, pval, pidx,
                                                        out_zq, out_idx, rowsum);
        loss_kernel<<<1, 256, 0, stream>>>(rowsum, out_loss);
    }
}

// Round 4
// 287.490 us; speedup vs baseline: 5.1593x; 5.1593x over previous
//
#include <hip/hip_runtime.h>
#include <math.h>

#define N_ROWS 16384
#define K_CODES 4096
#define D_DIM 512
#define NCHUNK 8
#define KCHUNK (K_CODES / NCHUNK)
#define MARGIN 2.5e-3f
#define CAND_CAP 1024

typedef unsigned int uint32;
typedef unsigned short u16t;
typedef __attribute__((ext_vector_type(8))) short short8;
typedef __attribute__((ext_vector_type(4))) float f32x4;

__device__ __forceinline__ float fmul_(float a, float b) { return __fmul_rn(a, b); }
__device__ __forceinline__ float fadd_(float a, float b) { return __fadd_rn(a, b); }

// ---------------------------------------------------------------- rownorm
// Bit-exact emulation of np.sum(x*x, axis=1), rows of 512 (verified R2/R3).
__global__ void rownorm_np_kernel(const float* __restrict__ src, int nrows,
                                  float* __restrict__ out) {
    int gid = blockIdx.x * blockDim.x + threadIdx.x;
    int row = gid >> 2;
    int blk = gid & 3;
    if (row >= nrows) return;
    const float4* p = (const float4*)(src + (size_t)row * D_DIM + blk * 128);
    float4 v0 = p[0], v1 = p[1];
    float r0 = fmul_(v0.x, v0.x), r1 = fmul_(v0.y, v0.y);
    float r2 = fmul_(v0.z, v0.z), r3 = fmul_(v0.w, v0.w);
    float r4 = fmul_(v1.x, v1.x), r5 = fmul_(v1.y, v1.y);
    float r6 = fmul_(v1.z, v1.z), r7 = fmul_(v1.w, v1.w);
#pragma unroll
    for (int i = 1; i < 16; i++) {
        float4 w0 = p[2 * i], w1 = p[2 * i + 1];
        r0 = fadd_(r0, fmul_(w0.x, w0.x));
        r1 = fadd_(r1, fmul_(w0.y, w0.y));
        r2 = fadd_(r2, fmul_(w0.z, w0.z));
        r3 = fadd_(r3, fmul_(w0.w, w0.w));
        r4 = fadd_(r4, fmul_(w1.x, w1.x));
        r5 = fadd_(r5, fmul_(w1.y, w1.y));
        r6 = fadd_(r6, fmul_(w1.z, w1.z));
        r7 = fadd_(r7, fmul_(w1.w, w1.w));
    }
    float s = fadd_(fadd_(fadd_(r0, r1), fadd_(r2, r3)),
                    fadd_(fadd_(r4, r5), fadd_(r6, r7)));
    float u = __shfl_down(s, 1, 64);
    float t = fadd_(s, u);
    float w = __shfl_down(t, 2, 64);
    float tot = fadd_(t, w);
    if (blk == 0) out[row] = tot;
}

// ---------------------------------------------------------------- cvt bf16
__device__ __forceinline__ u16t f2bf(float x) {
    uint32 u = __float_as_uint(x);
    return (u16t)((u + 0x7fffu + ((u >> 16) & 1u)) >> 16);   // RNE
}
__global__ void cvt_bf16_kernel(const float* __restrict__ src,
                                u16t* __restrict__ dst, int n4) {
    int i = blockIdx.x * blockDim.x + threadIdx.x;
    if (i >= n4) return;
    float4 v = ((const float4*)src)[i];
    ushort4 o;
    o.x = f2bf(v.x); o.y = f2bf(v.y); o.z = f2bf(v.z); o.w = f2bf(v.w);
    ((ushort4*)dst)[i] = o;
}

// ---------------------------------------------------------------- phase 1
// bf16 MFMA GEMM; epilogue writes coarse scores s = cc - 2*z.c as bf16 to
// global (via padded LDS tile for coalesced 16B stores). Staging/fragment
// code identical to R3 coarse (verified absmax=0).
#define STS 136   // stile stride in u16 (272 B = 17*16, keeps b128 alignment)

__global__ __launch_bounds__(256) void score_gemm_kernel(
    const u16t* __restrict__ zb, const u16t* __restrict__ cbb,
    const float* __restrict__ cnorm, u16t* __restrict__ scores) {
    __shared__ alignas(16) u16t Ab[128 * 32];
    __shared__ alignas(16) u16t Bb[128 * 32];
    __shared__ alignas(16) u16t stile[128 * STS];

    const int t = threadIdx.x;
    const int bx = blockIdx.x;
    const int by = blockIdx.y;
    const int row0 = by * 128, k0 = bx * KCHUNK;
    const int w = t >> 6, lane = t & 63;
    const int wx = w & 1, wy = w >> 1;
    const int l15 = lane & 15, quad = lane >> 4;

    for (int kt = 0; kt < 4; kt++) {
        f32x4 acc[4][4];
#pragma unroll
        for (int i = 0; i < 4; i++)
#pragma unroll
            for (int j = 0; j < 4; j++) acc[i][j] = (f32x4){0.f, 0.f, 0.f, 0.f};

        for (int dt = 0; dt < 16; dt++) {
            __syncthreads();
#pragma unroll
            for (int q = 0; q < 2; q++) {
                int s = q * 256 + t;
                const u16t* ga = zb + (size_t)(row0 + (s >> 2)) * D_DIM + dt * 32 + (s & 3) * 8;
                __builtin_amdgcn_global_load_lds(
                    (const __attribute__((address_space(1))) void*)ga,
                    (__attribute__((address_space(3))) void*)((char*)Ab + q * 4096 + w * 1024),
                    16, 0, 0);
                const u16t* gb = cbb + (size_t)(k0 + kt * 128 + (s >> 2)) * D_DIM + dt * 32 + (s & 3) * 8;
                __builtin_amdgcn_global_load_lds(
                    (const __attribute__((address_space(1))) void*)gb,
                    (__attribute__((address_space(3))) void*)((char*)Bb + q * 4096 + w * 1024),
                    16, 0, 0);
            }
            __syncthreads();
            short8 a[4], b[4];
#pragma unroll
            for (int i = 0; i < 4; i++)
                a[i] = *(const short8*)((char*)Ab + (wy * 64 + i * 16 + l15) * 64 + quad * 16);
#pragma unroll
            for (int j = 0; j < 4; j++)
                b[j] = *(const short8*)((char*)Bb + (wx * 64 + j * 16 + l15) * 64 + quad * 16);
#pragma unroll
            for (int i = 0; i < 4; i++)
#pragma unroll
                for (int j = 0; j < 4; j++)
                    acc[i][j] = __builtin_amdgcn_mfma_f32_16x16x32_bf16(a[i], b[j], acc[i][j], 0, 0, 0);
        }
        // pack scores to LDS tile (row-major, padded stride)
#pragma unroll
        for (int j = 0; j < 4; j++) {
            int cl = wx * 64 + j * 16 + l15;
            float cn = cnorm[k0 + kt * 128 + cl];
#pragma unroll
            for (int i = 0; i < 4; i++) {
#pragma unroll
                for (int r = 0; r < 4; r++) {
                    int rl = wy * 64 + i * 16 + quad * 4 + r;
                    float s = fmaf(-2.f, acc[i][j][r], cn);
                    stile[rl * STS + cl] = f2bf(s);
                }
            }
        }
        __syncthreads();
        // coalesced store: 128 rows x 128 u16
        for (int idx = t; idx < 128 * 16; idx += 256) {
            int row = idx >> 4, seg = idx & 15;
            short8 v = *(const short8*)&stile[row * STS + seg * 8];
            *(short8*)(scores + (size_t)(row0 + row) * K_CODES + k0 + kt * 128 + seg * 8) = v;
        }
        // next kt's first __syncthreads (dt loop head) protects stile reuse
    }
}

// ---------------------------------------------------------------- phase 2
// One block per row: global coarse min over 4096 bf16 scores, select
// candidates <= min + MARGIN, exact numpy-fp32 dist on each (verified ops),
// first-occurrence argmin, fused STE write + rowsum.
__global__ __launch_bounds__(256) void scan_refine_kernel(
    const u16t* __restrict__ scores,
    const float* __restrict__ z, const float* __restrict__ cb,
    const float* __restrict__ zz, const float* __restrict__ cnorm,
    float* __restrict__ out_zq, float* __restrict__ out_idx,
    float* __restrict__ rowsum) {
    __shared__ float smin[256];
    __shared__ int clist[CAND_CAP];
    __shared__ int cnt;
    __shared__ float wbv[4];
    __shared__ int wbi[4];
    __shared__ float red[256];
    __shared__ int bcast;

    const int row = blockIdx.x;
    const int t = threadIdx.x;
    const int w = t >> 6, lane = t & 63;

    if (t == 0) cnt = 0;

    // load 16 bf16 scores per thread
    const u16t* srow = scores + (size_t)row * K_CODES + t * 16;
    short8 sv0 = *(const short8*)(srow);
    short8 sv1 = *(const short8*)(srow + 8);
    float f[16];
#pragma unroll
    for (int e = 0; e < 8; e++) {
        f[e]     = __uint_as_float(((uint32)(u16t)sv0[e]) << 16);
        f[e + 8] = __uint_as_float(((uint32)(u16t)sv1[e]) << 16);
    }
    float m = f[0];
#pragma unroll
    for (int e = 1; e < 16; e++) m = fminf(m, f[e]);
    smin[t] = m;
    __syncthreads();
    for (int st = 128; st; st >>= 1) {
        if (t < st) smin[t] = fminf(smin[t], smin[t + st]);
        __syncthreads();
    }
    const float thr = smin[0] + MARGIN;

    // candidate selection
#pragma unroll
    for (int e = 0; e < 16; e++) {
        if (f[e] <= thr) {
            int pos = atomicAdd(&cnt, 1);
            if (pos < CAND_CAP) clist[pos] = t * 16 + e;
        }
    }
    __syncthreads();
    const int C = cnt < CAND_CAP ? cnt : CAND_CAP;

    // exact np-fp32 dist per candidate (wave-per-candidate, verified R3 ops)
    const float* zr = z + (size_t)row * D_DIM;
    float4 z0 = *(const float4*)(zr + lane * 8);
    float4 z1 = *(const float4*)(zr + lane * 8 + 4);
    float zzr = zz[row];

    float bv = 3.4e38f;
    int bi = 0x7fffffff;
    for (int ci = w; ci < C; ci += 4) {
        int k = clist[ci];
        const float* cr = cb + (size_t)k * D_DIM;
        float4 c0 = *(const float4*)(cr + lane * 8);
        float4 c1 = *(const float4*)(cr + lane * 8 + 4);
        float d = fmul_(z0.x, c0.x);
        d = fmaf(z0.y, c0.y, d); d = fmaf(z0.z, c0.z, d); d = fmaf(z0.w, c0.w, d);
        d = fmaf(z1.x, c1.x, d); d = fmaf(z1.y, c1.y, d);
        d = fmaf(z1.z, c1.z, d); d = fmaf(z1.w, c1.w, d);
#pragma unroll
        for (int off = 1; off < 64; off <<= 1)
            d = fadd_(d, __shfl_xor(d, off, 64));
        float dist = fmaf(-2.f, d, fadd_(zzr, cnorm[k]));
        // list order nondeterministic -> full (value, index) tie-break
        if (dist < bv || (dist == bv && k < bi)) { bv = dist; bi = k; }
    }
    if (lane == 0) { wbv[w] = bv; wbi[w] = bi; }
    __syncthreads();
    if (t == 0) {
        float B = wbv[0]; int I = wbi[0];
#pragma unroll
        for (int i = 1; i < 4; i++) {
            float v = wbv[i]; int ii = wbi[i];
            if (v < B || (v == B && ii < I)) { B = v; I = ii; }
        }
        bcast = I;
        out_idx[row] = (float)I;
    }
    __syncthreads();
    const int K = bcast;
    const float* cq = cb + (size_t)K * D_DIM;
    float2 zv2 = *(const float2*)(zr + t * 2);
    float2 cv2 = *(const float2*)(cq + t * 2);
    float2 o;
    o.x = fadd_(zv2.x, __fsub_rn(cv2.x, zv2.x));
    o.y = fadd_(zv2.y, __fsub_rn(cv2.y, zv2.y));
    *(float2*)(out_zq + (size_t)row * D_DIM + t * 2) = o;
    float dx = zv2.x - cv2.x, dy = zv2.y - cv2.y;
    red[t] = dx * dx + dy * dy;
    __syncthreads();
    for (int st = 128; st; st >>= 1) {
        if (t < st) red[t] += red[t + st];
        __syncthreads();
    }
    if (t == 0) rowsum[row] = red[0];
}

// ---------------------------------------------------------------- loss
__global__ void loss_kernel(const float* __restrict__ rowsum,
                            float* __restrict__ out_loss) {
    __shared__ float sm[256];
    float s = 0.f;
    for (int i = threadIdx.x; i < N_ROWS; i += 256) s += rowsum[i];
    sm[threadIdx.x] = s;
    __syncthreads();
    for (int st = 128; st; st >>= 1) {
        if (threadIdx.x < st) sm[threadIdx.x] += sm[threadIdx.x + st];
        __syncthreads();
    }
    if (threadIdx.x == 0)
        *out_loss = 1.25f * sm[0] / (float)(N_ROWS * D_DIM);
}

// ================================================================ fallback
// (verified round-2 fp32 path, used only if ws_size too small)
#define BM 128
#define BN 128
#define BK 16
#define TM 8
#define TN 8

__global__ __launch_bounds__(256, 4) void vq_argmin_kernel(
    const float* __restrict__ z, const float* __restrict__ cb,
    const float* __restrict__ zz, const float* __restrict__ cnorm,
    float* __restrict__ pval, int* __restrict__ pidx) {
    __shared__ float As[BK][BM + 4];
    __shared__ float Bs[BK][BN + 4];
    __shared__ float rv[BM][17];
    __shared__ int   ri[BM][17];

    const int bx = blockIdx.x;
    const int by = blockIdx.y;
    const int row0 = by * BM;
    const int k0 = bx * KCHUNK;
    const int t = threadIdx.x;
    const int tx = t & 15;
    const int ty = t >> 4;

    float minv[TM];
    int   mini[TM];
#pragma unroll
    for (int i = 0; i < TM; i++) { minv[i] = 3.4e38f; mini[i] = 0; }
    float zrow[TM];
#pragma unroll
    for (int i = 0; i < TM; i++) zrow[i] = zz[row0 + ty * TM + i];
    const int sr = t >> 1;
    const int sdq = (t & 1) * 8;

    for (int kt = 0; kt < KCHUNK / BN; kt++) {
        const int col0 = k0 + kt * BN;
        float acc[TM][TN];
#pragma unroll
        for (int i = 0; i < TM; i++)
#pragma unroll
            for (int j = 0; j < TN; j++) acc[i][j] = 0.f;
        for (int dt = 0; dt < D_DIM; dt += BK) {
            {
                const float* src = z + (size_t)(row0 + sr) * D_DIM + dt + sdq;
                float4 v0 = *(const float4*)(src);
                float4 v1 = *(const float4*)(src + 4);
                As[sdq + 0][sr] = v0.x; As[sdq + 1][sr] = v0.y;
                As[sdq + 2][sr] = v0.z; As[sdq + 3][sr] = v0.w;
                As[sdq + 4][sr] = v1.x; As[sdq + 5][sr] = v1.y;
                As[sdq + 6][sr] = v1.z; As[sdq + 7][sr] = v1.w;
                const float* srcb = cb + (size_t)(col0 + sr) * D_DIM + dt + sdq;
                float4 w0 = *(const float4*)(srcb);
                float4 w1 = *(const float4*)(srcb + 4);
                Bs[sdq + 0][sr] = w0.x; Bs[sdq + 1][sr] = w0.y;
                Bs[sdq + 2][sr] = w0.z; Bs[sdq + 3][sr] = w0.w;
                Bs[sdq + 4][sr] = w1.x; Bs[sdq + 5][sr] = w1.y;
                Bs[sdq + 6][sr] = w1.z; Bs[sdq + 7][sr] = w1.w;
            }
            __syncthreads();
#pragma unroll
            for (int d = 0; d < BK; d++) {
                float a[TM], b[TN];
#pragma unroll
                for (int i = 0; i < TM; i++) a[i] = As[d][ty * TM + i];
#pragma unroll
                for (int j = 0; j < TN; j++) b[j] = Bs[d][tx * TN + j];
#pragma unroll
                for (int i = 0; i < TM; i++)
#pragma unroll
                    for (int j = 0; j < TN; j++)
                        acc[i][j] = fmaf(a[i], b[j], acc[i][j]);
            }
            __syncthreads();
        }
#pragma unroll
        for (int j = 0; j < TN; j++) {
            const int col = col0 + tx * TN + j;
            const float cn = cnorm[col];
#pragma unroll
            for (int i = 0; i < TM; i++) {
                float s1 = fadd_(zrow[i], cn);
                float s = fmaf(-2.f, acc[i][j], s1);
                if (s < minv[i]) { minv[i] = s; mini[i] = col; }
            }
        }
    }
#pragma unroll
    for (int i = 0; i < TM; i++) {
        rv[ty * TM + i][tx] = minv[i];
        ri[ty * TM + i][tx] = mini[i];
    }
    __syncthreads();
    if (t < BM) {
        float bv = rv[t][0];
        int   bi = ri[t][0];
#pragma unroll
        for (int x = 1; x < 16; x++) {
            float v = rv[t][x]; int ii = ri[t][x];
            if (v < bv || (v == bv && ii < bi)) { bv = v; bi = ii; }
        }
        pval[(size_t)(row0 + t) * NCHUNK + bx] = bv;
        pidx[(size_t)(row0 + t) * NCHUNK + bx] = bi;
    }
}

__global__ void finalize_kernel(const float* __restrict__ z,
                                const float* __restrict__ cb,
                                const float* __restrict__ pval,
                                const int* __restrict__ pidx,
                                float* __restrict__ out_zq,
                                float* __restrict__ out_idx,
                                float* __restrict__ rowsum) {
    int row = (blockIdx.x * blockDim.x + threadIdx.x) >> 6;
    int lane = threadIdx.x & 63;
    if (row >= N_ROWS) return;
    float bv = pval[(size_t)row * NCHUNK];
    int   bi = pidx[(size_t)row * NCHUNK];
#pragma unroll
    for (int c = 1; c < NCHUNK; c++) {
        float v = pval[(size_t)row * NCHUNK + c];
        int  ii = pidx[(size_t)row * NCHUNK + c];
        if (v < bv || (v == bv && ii < bi)) { bv = v; bi = ii; }
    }
    const float4* zr = (const float4*)(z + (size_t)row * D_DIM);
    const float4* cr = (const float4*)(cb + (size_t)bi * D_DIM);
    float4* orow = (float4*)(out_zq + (size_t)row * D_DIM);
    float s = 0.f;
#pragma unroll
    for (int i = 0; i < 2; i++) {
        float4 zv = zr[i * 64 + lane];
        float4 cv = cr[i * 64 + lane];
        float4 o;
        o.x = fadd_(zv.x, __fsub_rn(cv.x, zv.x));
        o.y = fadd_(zv.y, __fsub_rn(cv.y, zv.y));
        o.z = fadd_(zv.z, __fsub_rn(cv.z, zv.z));
        o.w = fadd_(zv.w, __fsub_rn(cv.w, zv.w));
        orow[i * 64 + lane] = o;
        float dx = zv.x - cv.x, dy = zv.y - cv.y;
        float dz = zv.z - cv.z, dw = zv.w - cv.w;
        s += dx * dx + dy * dy + dz * dz + dw * dw;
    }
#pragma unroll
    for (int off = 32; off; off >>= 1) s += __shfl_down(s, off, 64);
    if (lane == 0) {
        rowsum[row] = s;
        out_idx[row] = (float)bi;
    }
}

// ---------------------------------------------------------------- launch
extern "C" void kernel_launch(void* const* d_in, const int* in_sizes, int n_in,
                              void* d_out, int out_size, void* d_ws, size_t ws_size,
                              hipStream_t stream) {
    const float* z  = (const float*)d_in[0];
    const float* cb = (const float*)d_in[1];
    float* out      = (float*)d_out;
    float* out_zq   = out;
    float* out_idx  = out + (size_t)N_ROWS * D_DIM;
    float* out_loss = out_idx + N_ROWS;

    float* zz     = (float*)d_ws;                          // 16384 f32
    float* cnorm  = zz + N_ROWS;                           // 4096 f32
    float* rowsum = cnorm + K_CODES;                       // 16384 f32
    u16t*  z_bf   = (u16t*)(rowsum + N_ROWS);              // 16384*512 u16
    u16t*  cb_bf  = z_bf + (size_t)N_ROWS * D_DIM;         // 4096*512 u16
    u16t*  scores = cb_bf + (size_t)K_CODES * D_DIM;       // 16384*4096 u16
    const size_t WS_NEEDED = (size_t)(N_ROWS + K_CODES + N_ROWS) * 4
                           + (size_t)N_ROWS * D_DIM * 2
                           + (size_t)K_CODES * D_DIM * 2
                           + (size_t)N_ROWS * K_CODES * 2;

    if (ws_size >= WS_NEEDED) {
        cvt_bf16_kernel<<<(N_ROWS * D_DIM / 4 + 255) / 256, 256, 0, stream>>>(z, z_bf, N_ROWS * D_DIM / 4);
        cvt_bf16_kernel<<<(K_CODES * D_DIM / 4 + 255) / 256, 256, 0, stream>>>(cb, cb_bf, K_CODES * D_DIM / 4);
        rownorm_np_kernel<<<(N_ROWS * 4) / 256, 256, 0, stream>>>(z, N_ROWS, zz);
        rownorm_np_kernel<<<(K_CODES * 4) / 256, 256, 0, stream>>>(cb, K_CODES, cnorm);

        dim3 g1(NCHUNK, N_ROWS / 128);
        score_gemm_kernel<<<g1, 256, 0, stream>>>(z_bf, cb_bf, cnorm, scores);
        scan_refine_kernel<<<N_ROWS, 256, 0, stream>>>(scores, z, cb, zz, cnorm,
                                                       out_zq, out_idx, rowsum);
        loss_kernel<<<1, 256, 0, stream>>>(rowsum, out_loss);
    } else {
        // fallback: verified round-2 fp32 path (~1 MB ws)
        float* pval = rowsum + N_ROWS;
        int*   pidx = (int*)(pval + (size_t)N_ROWS * NCHUNK);
        rownorm_np_kernel<<<(N_ROWS * 4) / 256, 256, 0, stream>>>(z, N_ROWS, zz);
        rownorm_np_kernel<<<(K_CODES * 4) / 256, 256, 0, stream>>>(cb, K_CODES, cnorm);
        dim3 g2(NCHUNK, N_ROWS / BM);
        vq_argmin_kernel<<<g2, 256, 0, stream>>>(z, cb, zz, cnorm, pval, pidx);
        finalize_kernel<<<N_ROWS / 4, 256, 0, stream>>>(z, cb, pval, pidx,
                                                        out_zq, out_idx, rowsum);
        loss_kernel<<<1, 256, 0, stream>>>(rowsum, out_loss);
    }
}